// Round 1
// 301.933 us; speedup vs baseline: 1.0566x; 1.0566x over previous
//
#include <hip/hip_runtime.h>
#include <hip/hip_fp16.h>

#define NN 50000
#define NE 800000

// ======== gemm1 (x@W1 -> fp16 T) merged with edge count+rank ====
// GEMM blocks: 64 nodes/block, 4-node x 4-feat reg tile. 16 FMA per LDS
// b128 read (was 8) -> LDS pipe and VALU balanced ~1:1, more independent
// global loads in flight per thread.
// Hist blocks: 4 edges/thread via int4; atomicAdd RETURNS the old count =
// the edge's rank within its dst row. rank[] lets k_scatter run atomic-free.

__global__ __launch_bounds__(256) void k_gemm1_count(
    const float* __restrict__ A, const float* __restrict__ W,
    __half* __restrict__ T, int n,
    const int* __restrict__ dst, int* __restrict__ cnt,
    int* __restrict__ rank, int E, int gemmBlocks)
{
    __shared__ float wlds[128 * 64];     // 32KB (hist blocks ignore)
    int tid = threadIdx.x;

    if ((int)blockIdx.x >= gemmBlocks) {
        // 1024 edges/block, 4 per thread, int4 in / int4 out (coalesced).
        int base = ((int)blockIdx.x - gemmBlocks) * 1024 + tid * 4;
        if (base < E) {
            int4 d4 = *(const int4*)&dst[base];
            int4 r4;
            r4.x = atomicAdd(&cnt[d4.x], 1);
            r4.y = atomicAdd(&cnt[d4.y], 1);
            r4.z = atomicAdd(&cnt[d4.z], 1);
            r4.w = atomicAdd(&cnt[d4.w], 1);
            *(int4*)&rank[base] = r4;
        }
        return;
    }

    const int K = 128;
    for (int i = tid; i < K * 64; i += 256) wlds[i] = W[i];   // F=64: direct
    __syncthreads();

    int fg = tid & 15;            // feats fg*4 .. fg*4+3
    int slot = tid >> 4;          // 16 slots x 4 nodes = 64 nodes/block
    int nodebase = blockIdx.x * 64 + slot * 4;

    float4 acc[4] = {};
    #pragma unroll 2
    for (int k = 0; k < K; k += 4) {
        float4 a[4];
        #pragma unroll
        for (int r = 0; r < 4; ++r) {
            int node = nodebase + r;
            a[r] = (node < n) ? *(const float4*)&A[node * K + k]
                              : float4{0.f, 0.f, 0.f, 0.f};
        }
        #pragma unroll
        for (int kk = 0; kk < 4; ++kk) {
            float4 wv = *(const float4*)&wlds[(k + kk) * 64 + fg * 4];
            #pragma unroll
            for (int r = 0; r < 4; ++r) {
                float av = (kk == 0) ? a[r].x : (kk == 1) ? a[r].y
                         : (kk == 2) ? a[r].z : a[r].w;
                acc[r].x += av * wv.x;
                acc[r].y += av * wv.y;
                acc[r].z += av * wv.z;
                acc[r].w += av * wv.w;
            }
        }
    }
    #pragma unroll
    for (int r = 0; r < 4; ++r) {
        int node = nodebase + r;
        if (node < n) {
            __half2 h[2];
            h[0] = __floats2half2_rn(acc[r].x, acc[r].y);
            h[1] = __floats2half2_rn(acc[r].z, acc[r].w);
            *(uint2*)&T[node * 64 + fg * 4] = *(uint2*)h;
        }
    }
}

// ======== scan (3-kernel scan collapsed to 2; R4: 1-block scan = 123us) ===

__global__ __launch_bounds__(256) void k_scan1(const int* __restrict__ cnt,
                                               int* __restrict__ rowstart,
                                               int* __restrict__ sums, int n) {
    __shared__ int s[256];
    int t = threadIdx.x, gid = blockIdx.x * 256 + t;
    int v = (gid < n) ? cnt[gid] : 0;
    s[t] = v; __syncthreads();
    for (int off = 1; off < 256; off <<= 1) {
        int x = (t >= off) ? s[t - off] : 0;
        __syncthreads();
        s[t] += x; __syncthreads();
    }
    if (gid < n) rowstart[gid] = s[t] - v;   // block-local exclusive
    if (t == 255) sums[blockIdx.x] = s[t];
}

// block b adds prefix = sum(sums[0..b)) and computes dinv. nb<=256.
__global__ __launch_bounds__(256) void k_scan23(const int* __restrict__ sums,
                                                int* __restrict__ rowstart,
                                                const int* __restrict__ cnt,
                                                float* __restrict__ dinv, int n) {
    __shared__ int s[256];
    int t = threadIdx.x, b = blockIdx.x;
    s[t] = (t < b) ? sums[t] : 0;
    __syncthreads();
    for (int off = 128; off > 0; off >>= 1) {
        if (t < off) s[t] += s[t + off];
        __syncthreads();
    }
    int prefix = s[0];
    int gid = b * 256 + t;
    if (gid < n) {
        rowstart[gid] += prefix;
        dinv[gid] = rsqrtf((float)cnt[gid] + 1.0f);   // deg incl. self loop
    }
}

// ======== scatter: ATOMIC-FREE now. p = rowstart[dst] + rank[e]. ========
// 4 edges/thread, int4 streamed reads; only dinv/rowstart gathers (L2-resident
// 200KB each) and the 8B csr scatter writes remain irregular.

__global__ __launch_bounds__(256) void k_scatter(const int* __restrict__ src,
                                                 const int* __restrict__ dst,
                                                 const int* __restrict__ rank,
                                                 const int* __restrict__ rowstart,
                                                 const float* __restrict__ dinv,
                                                 int2* __restrict__ csr, int E) {
    int base = ((int)blockIdx.x * 256 + threadIdx.x) * 4;
    if (base < E) {
        int4 s4 = *(const int4*)&src[base];
        int4 d4 = *(const int4*)&dst[base];
        int4 r4 = *(const int4*)&rank[base];
        int   s[4] = {s4.x, s4.y, s4.z, s4.w};
        int   d[4] = {d4.x, d4.y, d4.z, d4.w};
        int   r[4] = {r4.x, r4.y, r4.z, r4.w};
        #pragma unroll
        for (int u = 0; u < 4; ++u) {
            int p = rowstart[d[u]] + r[u];
            float w = dinv[s[u]] * dinv[d[u]];
            csr[p] = make_int2(s[u], __float_as_int(w));
        }
    }
}

// ======== fused: gather (bias_in + relu) then @W (64 x F_OUT) -> fp16 ====
// 8 nodes/block (4 waves x 2 per wave). Gather as before (fp16 rows, fp32
// accum). Aggregated row round-trips through LDS g[8][64]; each half-wave
// reads only its own row (plus __syncthreads for safety). W k-major in LDS,
// lane fl reads W[k][2fl..2fl+1] as float2 (2-way bank alias = free), g via
// ds_read_b128 broadcast. GEMM LDS/VALU work hides under other waves'
// gather-miss latency.

#define GB 16

template <int F_OUT>
__global__ __launch_bounds__(256) void k_fused(
    const __half* __restrict__ Tin, const int2* __restrict__ csr,
    const int* __restrict__ rowstart, const int* __restrict__ cnt,
    const float* __restrict__ dinv, const float* __restrict__ bias_in,
    const float* __restrict__ W, __half* __restrict__ Tout, int n)
{
    __shared__ float wlds[64 * F_OUT];
    __shared__ float g[8 * 64];
    int tid = threadIdx.x;
    for (int i = tid; i < 64 * F_OUT; i += 256) wlds[i] = W[i];  // k-major

    int wid = tid >> 6, lane = tid & 63;
    int half = lane >> 5, fl = lane & 31;
    int slot = wid * 2 + half;
    int node = blockIdx.x * 8 + slot;
    bool valid = node < n;

    float2 acc = {0.f, 0.f};
    if (valid) {
        float di = dinv[node];
        float2 tv = __half22float2(*(const __half2*)&Tin[node * 64 + fl * 2]);
        acc.x = tv.x * di * di;                    // self loop
        acc.y = tv.y * di * di;
        int s0 = rowstart[node], c = cnt[node];
        for (int j = 0; j < c; j += GB) {
            int   col[GB];
            float w[GB];
            #pragma unroll
            for (int u = 0; u < GB; ++u) {
                int idx = j + u;
                int2 cw = (idx < c) ? csr[s0 + idx] : make_int2(0, 0);
                col[u] = cw.x;
                w[u]   = __int_as_float(cw.y);
            }
            __half2 tv2[GB];
            #pragma unroll
            for (int u = 0; u < GB; ++u)
                tv2[u] = *(const __half2*)&Tin[col[u] * 64 + fl * 2];
            #pragma unroll
            for (int u = 0; u < GB; ++u) {
                float2 tf = __half22float2(tv2[u]);
                acc.x += w[u] * tf.x;
                acc.y += w[u] * tf.y;
            }
        }
        float2 b = *(const float2*)&bias_in[fl * 2];
        acc.x = fmaxf(acc.x + b.x, 0.f);           // relu (both fused layers)
        acc.y = fmaxf(acc.y + b.y, 0.f);
        *(float2*)&g[slot * 64 + fl * 2] = acc;
    }
    __syncthreads();    // also covers the W staging at the top

    if (valid && (fl * 2 + 1) < F_OUT) {
        float2 o = {0.f, 0.f};
        #pragma unroll 4
        for (int k = 0; k < 64; k += 4) {
            float4 gv = *(const float4*)&g[slot * 64 + k];
            #pragma unroll
            for (int kk = 0; kk < 4; ++kk) {
                float2 wv = *(const float2*)&wlds[(k + kk) * F_OUT + fl * 2];
                float gk = (kk == 0) ? gv.x : (kk == 1) ? gv.y
                         : (kk == 2) ? gv.z : gv.w;
                o.x += gk * wv.x;
                o.y += gk * wv.y;
            }
        }
        __half2 h = __floats2half2_rn(o.x, o.y);
        *(uint*)&Tout[node * F_OUT + fl * 2] = *(uint*)&h;
    }
}

// ======== final gather: fp16 Tin (F=40) -> +b3 -> fp32 out ========

__global__ __launch_bounds__(256) void k_gather_out(
    const __half* __restrict__ T, const int2* __restrict__ csr,
    const int* __restrict__ rowstart, const int* __restrict__ cnt,
    const float* __restrict__ dinv, const float* __restrict__ bias,
    float* __restrict__ OUT, int n, int F)
{
    int tid = threadIdx.x;
    int wid = tid >> 6, lane = tid & 63;
    int half = lane >> 5, fl = lane & 31;
    int node = blockIdx.x * 8 + wid * 2 + half;
    if (node >= n) return;
    int f0 = fl * 2;
    bool factive = (f0 + 1) < F;
    float di = dinv[node];

    float2 acc = {0.f, 0.f};
    if (factive) {
        float2 tv = __half22float2(*(const __half2*)&T[node * F + f0]);
        acc.x = tv.x * di * di;
        acc.y = tv.y * di * di;
    }
    int s0 = rowstart[node], c = cnt[node];
    for (int j = 0; j < c; j += GB) {
        int   col[GB];
        float w[GB];
        #pragma unroll
        for (int u = 0; u < GB; ++u) {
            int idx = j + u;
            int2 cw = (idx < c) ? csr[s0 + idx] : make_int2(0, 0);
            col[u] = cw.x;
            w[u]   = __int_as_float(cw.y);
        }
        __half2 tv[GB];
        #pragma unroll
        for (int u = 0; u < GB; ++u)
            tv[u] = factive ? *(const __half2*)&T[col[u] * F + f0] : __half2{};
        #pragma unroll
        for (int u = 0; u < GB; ++u) {
            float2 tf = __half22float2(tv[u]);
            acc.x += w[u] * tf.x;
            acc.y += w[u] * tf.y;
        }
    }
    if (factive) {
        float2 b = *(const float2*)&bias[f0];
        *(float2*)&OUT[node * F + f0] = make_float2(acc.x + b.x, acc.y + b.y);
    }
}

// ---------------- launch ----------------

extern "C" void kernel_launch(void* const* d_in, const int* in_sizes, int n_in,
                              void* d_out, int out_size, void* d_ws, size_t ws_size,
                              hipStream_t stream) {
    const float* x  = (const float*)d_in[0];
    const int*   ei = (const int*)d_in[1];
    const float* W1 = (const float*)d_in[2];
    const float* b1 = (const float*)d_in[3];
    const float* W2 = (const float*)d_in[4];
    const float* b2 = (const float*)d_in[5];
    const float* W3 = (const float*)d_in[6];
    const float* b3 = (const float*)d_in[7];
    float* out = (float*)d_out;

    const int N = NN, E = NE;
    const int* src = ei;
    const int* dst = ei + E;

    // workspace (re-poisoned to 0xAA before every call)
    int*    cnt      = (int*)d_ws;                       // N
    int*    rowstart = cnt + N;                          // N
    float*  dinv     = (float*)(rowstart + N);           // N
    int*    sums     = (int*)(dinv + N);                 // 256
    int*    rank     = sums + 256;                       // E (intra-row rank)
    int2*   csr      = (int2*)(rank + E);                // E
    __half* tA       = (__half*)(csr + E);               // N*64 fp16
    __half* tB       = tA + (size_t)N * 64;              // N*64 fp16
    __half* tC       = tB + (size_t)N * 64;              // N*40 fp16

    hipMemsetAsync(cnt, 0, sizeof(int) * N, stream);

    int eb4 = (E + 1023) / 1024;    // 782 (4 edges/thread)
    int nb  = (N + 255) / 256;      // 196
    int gb  = (N + 63) / 64;        // 782 (64 nodes/block)
    int fb  = (N + 7) / 8;          // 6250

    k_gemm1_count<<<gb + eb4, 256, 0, stream>>>(x, W1, tA, N, dst, cnt, rank, E, gb);
    k_scan1 <<<nb, 256, 0, stream>>>(cnt, rowstart, sums, N);
    k_scan23<<<nb, 256, 0, stream>>>(sums, rowstart, cnt, dinv, N);
    k_scatter<<<eb4, 256, 0, stream>>>(src, dst, rank, rowstart, dinv, csr, E);

    k_fused<64><<<fb, 256, 0, stream>>>(tA, csr, rowstart, cnt, dinv, b1, W2, tB, N);
    k_fused<40><<<fb, 256, 0, stream>>>(tB, csr, rowstart, cnt, dinv, b2, W3, tC, N);
    k_gather_out<<<fb, 256, 0, stream>>>(tC, csr, rowstart, cnt, dinv, b3, out, N, 40);
}

// Round 2
// 295.573 us; speedup vs baseline: 1.0793x; 1.0215x over previous
//
#include <hip/hip_runtime.h>
#include <hip/hip_fp16.h>

#define NN 50000
#define NE 800000
#define CHUNK 8192            // edges per hist block (2^13; scatter uses >>13)
#define NB 98                 // ceil(NE/CHUNK)
#define HW 25000              // packed histogram words = ceil(NN/2)

// ======== k_hist: per-chunk LDS histogram, ZERO global atomics ========
// 50K bins as 2x uint16 packed per uint32 -> 100KB LDS (1 block/CU).
// LDS atomicAdd returns old packed word => local rank of the edge within
// (chunk, dst). Per-chunk-per-node count <= 8192 so halves never carry.

__global__ __launch_bounds__(256) void k_hist(
    const int* __restrict__ dst, unsigned int* __restrict__ partial,
    unsigned short* __restrict__ lrank, int E)
{
    __shared__ unsigned int hb[HW];
    int tid = threadIdx.x, b = blockIdx.x;
    for (int i = tid; i < HW; i += 256) hb[i] = 0;
    __syncthreads();

    int base = b * CHUNK;
    int end  = min(base + CHUNK, E);
    for (int e = base + tid; e < end; e += 256) {
        int d = dst[e];
        unsigned sh  = (unsigned)(d & 1) << 4;
        unsigned old = atomicAdd(&hb[d >> 1], 1u << sh);
        lrank[e] = (unsigned short)((old >> sh) & 0xFFFFu);
    }
    __syncthreads();

    unsigned int* prow = partial + (size_t)b * HW;
    for (int i = tid; i < HW; i += 256) prow[i] = hb[i];
}

// ======== gemm1 (x@W1 -> fp16 T) merged with partial-matrix scan ====
// GEMM blocks: 64 nodes/block, 4-node x 4-feat reg tile (unchanged R1 math).
// Scan blocks: thread per packed word scans the NB block-histograms into
// exclusive per-(chunk,node) offsets in place, and emits cnt[node].
// Independent work, merged to hide the ~20MB scan traffic under the gemm.

__global__ __launch_bounds__(256) void k_gemm1_scan(
    const float* __restrict__ A, const float* __restrict__ W,
    __half* __restrict__ T, int n,
    unsigned int* __restrict__ partial, int* __restrict__ cnt, int gemmBlocks)
{
    __shared__ float wlds[128 * 64];     // 32KB (scan blocks ignore)
    int tid = threadIdx.x;

    if ((int)blockIdx.x >= gemmBlocks) {
        int w = ((int)blockIdx.x - gemmBlocks) * 256 + tid;
        if (w < HW) {
            unsigned s0 = 0, s1 = 0;
            unsigned int* p = partial + w;
            for (int b = 0; b < NB; ++b) {
                unsigned v = p[(size_t)b * HW];
                p[(size_t)b * HW] = s0 | (s1 << 16);   // exclusive, packed
                s0 += v & 0xFFFFu;
                s1 += v >> 16;
            }
            int d1 = w * 2 + 1;
            cnt[w * 2] = (int)s0;                      // w*2 < 50000 always
            if (d1 < n) cnt[d1] = (int)s1;
        }
        return;
    }

    const int K = 128;
    for (int i = tid; i < K * 64; i += 256) wlds[i] = W[i];   // F=64: direct
    __syncthreads();

    int fg = tid & 15;            // feats fg*4 .. fg*4+3
    int slot = tid >> 4;          // 16 slots x 4 nodes = 64 nodes/block
    int nodebase = blockIdx.x * 64 + slot * 4;

    float4 acc[4] = {};
    #pragma unroll 2
    for (int k = 0; k < K; k += 4) {
        float4 a[4];
        #pragma unroll
        for (int r = 0; r < 4; ++r) {
            int node = nodebase + r;
            a[r] = (node < n) ? *(const float4*)&A[node * K + k]
                              : float4{0.f, 0.f, 0.f, 0.f};
        }
        #pragma unroll
        for (int kk = 0; kk < 4; ++kk) {
            float4 wv = *(const float4*)&wlds[(k + kk) * 64 + fg * 4];
            #pragma unroll
            for (int r = 0; r < 4; ++r) {
                float av = (kk == 0) ? a[r].x : (kk == 1) ? a[r].y
                         : (kk == 2) ? a[r].z : a[r].w;
                acc[r].x += av * wv.x;
                acc[r].y += av * wv.y;
                acc[r].z += av * wv.z;
                acc[r].w += av * wv.w;
            }
        }
    }
    #pragma unroll
    for (int r = 0; r < 4; ++r) {
        int node = nodebase + r;
        if (node < n) {
            __half2 h[2];
            h[0] = __floats2half2_rn(acc[r].x, acc[r].y);
            h[1] = __floats2half2_rn(acc[r].z, acc[r].w);
            *(uint2*)&T[node * 64 + fg * 4] = *(uint2*)h;
        }
    }
}

// ======== scan (unchanged): rowstart = excl-scan(cnt), dinv ========

__global__ __launch_bounds__(256) void k_scan1(const int* __restrict__ cnt,
                                               int* __restrict__ rowstart,
                                               int* __restrict__ sums, int n) {
    __shared__ int s[256];
    int t = threadIdx.x, gid = blockIdx.x * 256 + t;
    int v = (gid < n) ? cnt[gid] : 0;
    s[t] = v; __syncthreads();
    for (int off = 1; off < 256; off <<= 1) {
        int x = (t >= off) ? s[t - off] : 0;
        __syncthreads();
        s[t] += x; __syncthreads();
    }
    if (gid < n) rowstart[gid] = s[t] - v;   // block-local exclusive
    if (t == 255) sums[blockIdx.x] = s[t];
}

__global__ __launch_bounds__(256) void k_scan23(const int* __restrict__ sums,
                                                int* __restrict__ rowstart,
                                                const int* __restrict__ cnt,
                                                float* __restrict__ dinv, int n) {
    __shared__ int s[256];
    int t = threadIdx.x, b = blockIdx.x;
    s[t] = (t < b) ? sums[t] : 0;
    __syncthreads();
    for (int off = 128; off > 0; off >>= 1) {
        if (t < off) s[t] += s[t + off];
        __syncthreads();
    }
    int prefix = s[0];
    int gid = b * 256 + t;
    if (gid < n) {
        rowstart[gid] += prefix;
        dinv[gid] = rsqrtf((float)cnt[gid] + 1.0f);   // deg incl. self loop
    }
}

// ======== scatter: fully atomic-free ========
// p = rowstart[d] + partial[chunk][d] + lrank[e]. partial row (100KB) is
// L2-resident for the block's fixed chunk.

__global__ __launch_bounds__(256) void k_scatter(const int* __restrict__ src,
                                                 const int* __restrict__ dst,
                                                 const unsigned short* __restrict__ lrank,
                                                 const unsigned int* __restrict__ partial,
                                                 const int* __restrict__ rowstart,
                                                 const float* __restrict__ dinv,
                                                 int2* __restrict__ csr, int E) {
    int base = ((int)blockIdx.x * 256 + threadIdx.x) * 4;
    if (base < E) {                       // E % 4 == 0 -> full int4 in bounds
        const unsigned int* prow = partial + (size_t)(base >> 13) * HW;
        int4 s4 = *(const int4*)&src[base];
        int4 d4 = *(const int4*)&dst[base];
        uint2 l2 = *(const uint2*)&lrank[base];
        int s[4] = {s4.x, s4.y, s4.z, s4.w};
        int d[4] = {d4.x, d4.y, d4.z, d4.w};
        unsigned lr[4] = {l2.x & 0xFFFFu, l2.x >> 16, l2.y & 0xFFFFu, l2.y >> 16};
        #pragma unroll
        for (int u = 0; u < 4; ++u) {
            unsigned off = (prow[d[u] >> 1] >> ((unsigned)(d[u] & 1) << 4)) & 0xFFFFu;
            int p = rowstart[d[u]] + (int)off + (int)lr[u];
            float w = dinv[s[u]] * dinv[d[u]];
            csr[p] = make_int2(s[u], __float_as_int(w));
        }
    }
}

// ======== fused: gather (bias_in + relu) then @W (64 x F_OUT) -> fp16 ====

#define GB 16

template <int F_OUT>
__global__ __launch_bounds__(256) void k_fused(
    const __half* __restrict__ Tin, const int2* __restrict__ csr,
    const int* __restrict__ rowstart, const int* __restrict__ cnt,
    const float* __restrict__ dinv, const float* __restrict__ bias_in,
    const float* __restrict__ W, __half* __restrict__ Tout, int n)
{
    __shared__ float wlds[64 * F_OUT];
    __shared__ float g[8 * 64];
    int tid = threadIdx.x;
    for (int i = tid; i < 64 * F_OUT; i += 256) wlds[i] = W[i];  // k-major

    int wid = tid >> 6, lane = tid & 63;
    int half = lane >> 5, fl = lane & 31;
    int slot = wid * 2 + half;
    int node = blockIdx.x * 8 + slot;
    bool valid = node < n;

    float2 acc = {0.f, 0.f};
    if (valid) {
        float di = dinv[node];
        float2 tv = __half22float2(*(const __half2*)&Tin[node * 64 + fl * 2]);
        acc.x = tv.x * di * di;                    // self loop
        acc.y = tv.y * di * di;
        int s0 = rowstart[node], c = cnt[node];
        for (int j = 0; j < c; j += GB) {
            int   col[GB];
            float w[GB];
            #pragma unroll
            for (int u = 0; u < GB; ++u) {
                int idx = j + u;
                int2 cw = (idx < c) ? csr[s0 + idx] : make_int2(0, 0);
                col[u] = cw.x;
                w[u]   = __int_as_float(cw.y);
            }
            __half2 tv2[GB];
            #pragma unroll
            for (int u = 0; u < GB; ++u)
                tv2[u] = *(const __half2*)&Tin[col[u] * 64 + fl * 2];
            #pragma unroll
            for (int u = 0; u < GB; ++u) {
                float2 tf = __half22float2(tv2[u]);
                acc.x += w[u] * tf.x;
                acc.y += w[u] * tf.y;
            }
        }
        float2 b = *(const float2*)&bias_in[fl * 2];
        acc.x = fmaxf(acc.x + b.x, 0.f);           // relu (both fused layers)
        acc.y = fmaxf(acc.y + b.y, 0.f);
        *(float2*)&g[slot * 64 + fl * 2] = acc;
    }
    __syncthreads();    // also covers the W staging at the top

    if (valid && (fl * 2 + 1) < F_OUT) {
        float2 o = {0.f, 0.f};
        #pragma unroll 4
        for (int k = 0; k < 64; k += 4) {
            float4 gv = *(const float4*)&g[slot * 64 + k];
            #pragma unroll
            for (int kk = 0; kk < 4; ++kk) {
                float2 wv = *(const float2*)&wlds[(k + kk) * F_OUT + fl * 2];
                float gk = (kk == 0) ? gv.x : (kk == 1) ? gv.y
                         : (kk == 2) ? gv.z : gv.w;
                o.x += gk * wv.x;
                o.y += gk * wv.y;
            }
        }
        __half2 h = __floats2half2_rn(o.x, o.y);
        *(uint*)&Tout[node * F_OUT + fl * 2] = *(uint*)&h;
    }
}

// ======== final gather: fp16 Tin (F=40) -> +b3 -> fp32 out ========

__global__ __launch_bounds__(256) void k_gather_out(
    const __half* __restrict__ T, const int2* __restrict__ csr,
    const int* __restrict__ rowstart, const int* __restrict__ cnt,
    const float* __restrict__ dinv, const float* __restrict__ bias,
    float* __restrict__ OUT, int n, int F)
{
    int tid = threadIdx.x;
    int wid = tid >> 6, lane = tid & 63;
    int half = lane >> 5, fl = lane & 31;
    int node = blockIdx.x * 8 + wid * 2 + half;
    if (node >= n) return;
    int f0 = fl * 2;
    bool factive = (f0 + 1) < F;
    float di = dinv[node];

    float2 acc = {0.f, 0.f};
    if (factive) {
        float2 tv = __half22float2(*(const __half2*)&T[node * F + f0]);
        acc.x = tv.x * di * di;
        acc.y = tv.y * di * di;
    }
    int s0 = rowstart[node], c = cnt[node];
    for (int j = 0; j < c; j += GB) {
        int   col[GB];
        float w[GB];
        #pragma unroll
        for (int u = 0; u < GB; ++u) {
            int idx = j + u;
            int2 cw = (idx < c) ? csr[s0 + idx] : make_int2(0, 0);
            col[u] = cw.x;
            w[u]   = __int_as_float(cw.y);
        }
        __half2 tv[GB];
        #pragma unroll
        for (int u = 0; u < GB; ++u)
            tv[u] = factive ? *(const __half2*)&T[col[u] * F + f0] : __half2{};
        #pragma unroll
        for (int u = 0; u < GB; ++u) {
            float2 tf = __half22float2(tv[u]);
            acc.x += w[u] * tf.x;
            acc.y += w[u] * tf.y;
        }
    }
    if (factive) {
        float2 b = *(const float2*)&bias[f0];
        *(float2*)&OUT[node * F + f0] = make_float2(acc.x + b.x, acc.y + b.y);
    }
}

// ---------------- launch ----------------

extern "C" void kernel_launch(void* const* d_in, const int* in_sizes, int n_in,
                              void* d_out, int out_size, void* d_ws, size_t ws_size,
                              hipStream_t stream) {
    const float* x  = (const float*)d_in[0];
    const int*   ei = (const int*)d_in[1];
    const float* W1 = (const float*)d_in[2];
    const float* b1 = (const float*)d_in[3];
    const float* W2 = (const float*)d_in[4];
    const float* b2 = (const float*)d_in[5];
    const float* W3 = (const float*)d_in[6];
    const float* b3 = (const float*)d_in[7];
    float* out = (float*)d_out;

    const int N = NN, E = NE;
    const int* src = ei;
    const int* dst = ei + E;

    // workspace (re-poisoned before every call; everything written-before-read)
    int*    cnt      = (int*)d_ws;                           // N
    int*    rowstart = cnt + N;                               // N
    float*  dinv     = (float*)(rowstart + N);                // N
    int*    sums     = (int*)(dinv + N);                      // 256
    unsigned short* lrank = (unsigned short*)(sums + 256);    // E
    int2*   csr      = (int2*)(lrank + E);                    // E
    __half* tA       = (__half*)(csr + E);                    // N*64 fp16
    __half* tB       = tA + (size_t)N * 64;                   // N*64 fp16
    __half* tC       = tB + (size_t)N * 64;                   // N*40 fp16
    // partial matrix (NB x HW uint32 = 9.8MB) aliases tB..tC: fully consumed
    // by k_scatter, which runs before fused<64> writes tB.
    unsigned int* partial = (unsigned int*)tB;

    int eb4 = (E / 4 + 255) / 256;  // 782
    int nb  = (N + 255) / 256;      // 196
    int gb  = (N + 63) / 64;        // 782 (64 nodes/block)
    int snb = (HW + 255) / 256;     // 98 scan blocks
    int fb  = (N + 7) / 8;          // 6250

    k_hist<<<NB, 256, 0, stream>>>(dst, partial, lrank, E);
    k_gemm1_scan<<<gb + snb, 256, 0, stream>>>(x, W1, tA, N, partial, cnt, gb);
    k_scan1 <<<nb, 256, 0, stream>>>(cnt, rowstart, sums, N);
    k_scan23<<<nb, 256, 0, stream>>>(sums, rowstart, cnt, dinv, N);
    k_scatter<<<eb4, 256, 0, stream>>>(src, dst, lrank, partial, rowstart, dinv, csr, E);

    k_fused<64><<<fb, 256, 0, stream>>>(tA, csr, rowstart, cnt, dinv, b1, W2, tB, N);
    k_fused<40><<<fb, 256, 0, stream>>>(tB, csr, rowstart, cnt, dinv, b2, W3, tC, N);
    k_gather_out<<<fb, 256, 0, stream>>>(tC, csr, rowstart, cnt, dinv, b3, out, N, 40);
}

// Round 3
// 235.096 us; speedup vs baseline: 1.3569x; 1.2572x over previous
//
#include <hip/hip_runtime.h>
#include <hip/hip_fp16.h>

#define NN 50000
#define NE 800000
#define CHUNK 8192            // edges per hist block (2^13; scatter uses >>13)
#define NB 98                 // ceil(NE/CHUNK)
#define HW 25000              // packed histogram words = ceil(NN/2)

// ======== k_hist: per-chunk LDS histogram, ZERO global atomics ========
// 50K bins as 2x uint16 packed per uint32 -> 100KB LDS (1 block/CU).
// LDS atomicAdd returns old packed word => local rank of the edge within
// (chunk, dst). Per-chunk-per-node count <= 8192 so halves never carry.

__global__ __launch_bounds__(256) void k_hist(
    const int* __restrict__ dst, unsigned int* __restrict__ partial,
    unsigned short* __restrict__ lrank, int E)
{
    __shared__ unsigned int hb[HW];
    int tid = threadIdx.x, b = blockIdx.x;
    for (int i = tid; i < HW; i += 256) hb[i] = 0;
    __syncthreads();

    int base = b * CHUNK;
    int end  = min(base + CHUNK, E);
    for (int e = base + tid; e < end; e += 256) {
        int d = dst[e];
        unsigned sh  = (unsigned)(d & 1) << 4;
        unsigned old = atomicAdd(&hb[d >> 1], 1u << sh);
        lrank[e] = (unsigned short)((old >> sh) & 0xFFFFu);
    }
    __syncthreads();

    unsigned int* prow = partial + (size_t)b * HW;
    for (int i = tid; i < HW; i += 256) prow[i] = hb[i];
}

// ======== gemm1 (x@W1 -> fp16 T) merged with partial-matrix scan ====

__global__ __launch_bounds__(256) void k_gemm1_scan(
    const float* __restrict__ A, const float* __restrict__ W,
    __half* __restrict__ T, int n,
    unsigned int* __restrict__ partial, int* __restrict__ cnt, int gemmBlocks)
{
    __shared__ float wlds[128 * 64];     // 32KB (scan blocks ignore)
    int tid = threadIdx.x;

    if ((int)blockIdx.x >= gemmBlocks) {
        int w = ((int)blockIdx.x - gemmBlocks) * 256 + tid;
        if (w < HW) {
            unsigned s0 = 0, s1 = 0;
            unsigned int* p = partial + w;
            for (int b = 0; b < NB; ++b) {
                unsigned v = p[(size_t)b * HW];
                p[(size_t)b * HW] = s0 | (s1 << 16);   // exclusive, packed
                s0 += v & 0xFFFFu;
                s1 += v >> 16;
            }
            int d1 = w * 2 + 1;
            cnt[w * 2] = (int)s0;
            if (d1 < n) cnt[d1] = (int)s1;
        }
        return;
    }

    const int K = 128;
    for (int i = tid; i < K * 64; i += 256) wlds[i] = W[i];   // F=64: direct
    __syncthreads();

    int fg = tid & 15;            // feats fg*4 .. fg*4+3
    int slot = tid >> 4;          // 16 slots x 4 nodes = 64 nodes/block
    int nodebase = blockIdx.x * 64 + slot * 4;

    float4 acc[4] = {};
    #pragma unroll 2
    for (int k = 0; k < K; k += 4) {
        float4 a[4];
        #pragma unroll
        for (int r = 0; r < 4; ++r) {
            int node = nodebase + r;
            a[r] = (node < n) ? *(const float4*)&A[node * K + k]
                              : float4{0.f, 0.f, 0.f, 0.f};
        }
        #pragma unroll
        for (int kk = 0; kk < 4; ++kk) {
            float4 wv = *(const float4*)&wlds[(k + kk) * 64 + fg * 4];
            #pragma unroll
            for (int r = 0; r < 4; ++r) {
                float av = (kk == 0) ? a[r].x : (kk == 1) ? a[r].y
                         : (kk == 2) ? a[r].z : a[r].w;
                acc[r].x += av * wv.x;
                acc[r].y += av * wv.y;
                acc[r].z += av * wv.z;
                acc[r].w += av * wv.w;
            }
        }
    }
    #pragma unroll
    for (int r = 0; r < 4; ++r) {
        int node = nodebase + r;
        if (node < n) {
            __half2 h[2];
            h[0] = __floats2half2_rn(acc[r].x, acc[r].y);
            h[1] = __floats2half2_rn(acc[r].z, acc[r].w);
            *(uint2*)&T[node * 64 + fg * 4] = *(uint2*)h;
        }
    }
}

// ======== scans (unchanged) ========

__global__ __launch_bounds__(256) void k_scan1(const int* __restrict__ cnt,
                                               int* __restrict__ rowstart,
                                               int* __restrict__ sums, int n) {
    __shared__ int s[256];
    int t = threadIdx.x, gid = blockIdx.x * 256 + t;
    int v = (gid < n) ? cnt[gid] : 0;
    s[t] = v; __syncthreads();
    for (int off = 1; off < 256; off <<= 1) {
        int x = (t >= off) ? s[t - off] : 0;
        __syncthreads();
        s[t] += x; __syncthreads();
    }
    if (gid < n) rowstart[gid] = s[t] - v;
    if (t == 255) sums[blockIdx.x] = s[t];
}

__global__ __launch_bounds__(256) void k_scan23(const int* __restrict__ sums,
                                                int* __restrict__ rowstart,
                                                const int* __restrict__ cnt,
                                                float* __restrict__ dinv, int n) {
    __shared__ int s[256];
    int t = threadIdx.x, b = blockIdx.x;
    s[t] = (t < b) ? sums[t] : 0;
    __syncthreads();
    for (int off = 128; off > 0; off >>= 1) {
        if (t < off) s[t] += s[t + off];
        __syncthreads();
    }
    int prefix = s[0];
    int gid = b * 256 + t;
    if (gid < n) {
        rowstart[gid] += prefix;
        dinv[gid] = rsqrtf((float)cnt[gid] + 1.0f);
    }
}

// ======== scatter: atomic-free (unchanged) ========

__global__ __launch_bounds__(256) void k_scatter(const int* __restrict__ src,
                                                 const int* __restrict__ dst,
                                                 const unsigned short* __restrict__ lrank,
                                                 const unsigned int* __restrict__ partial,
                                                 const int* __restrict__ rowstart,
                                                 const float* __restrict__ dinv,
                                                 int2* __restrict__ csr, int E) {
    int base = ((int)blockIdx.x * 256 + threadIdx.x) * 4;
    if (base < E) {
        const unsigned int* prow = partial + (size_t)(base >> 13) * HW;
        int4 s4 = *(const int4*)&src[base];
        int4 d4 = *(const int4*)&dst[base];
        uint2 l2 = *(const uint2*)&lrank[base];
        int s[4] = {s4.x, s4.y, s4.z, s4.w};
        int d[4] = {d4.x, d4.y, d4.z, d4.w};
        unsigned lr[4] = {l2.x & 0xFFFFu, l2.x >> 16, l2.y & 0xFFFFu, l2.y >> 16};
        #pragma unroll
        for (int u = 0; u < 4; ++u) {
            unsigned off = (prow[d[u] >> 1] >> ((unsigned)(d[u] & 1) << 4)) & 0xFFFFu;
            int p = rowstart[d[u]] + (int)off + (int)lr[u];
            float w = dinv[s[u]] * dinv[d[u]];
            csr[p] = make_int2(s[u], __float_as_int(w));
        }
    }
}

// ======== fused octet kernel: gather (bias+relu) then @W -> fp16 ========
// 8 lanes per node ("octet"), 32 nodes/block. Each lane owns 8 feats
// (16B dwordx4 gathers = coalescing sweet spot; one gather instruction
// moves 8 edges across the wave's 8 octets). csr entries loaded
// cooperatively (lane l reads edge j+l) and spread via __shfl(w=8).
// Output GEMM is octet-local via shuffles: no LDS g buffer, no
// post-gather barrier -> waves retire independently (degree imbalance
// doesn't stall the block). Tout stride is 64 for all layers (F_OUT=40
// pads feats 40..63 with zeros so next gather reads aligned 128B lines).

template <int F_OUT>
__global__ __launch_bounds__(256, 4) void k_fused(
    const __half* __restrict__ Tin, const int2* __restrict__ csr,
    const int* __restrict__ rowstart, const int* __restrict__ cnt,
    const float* __restrict__ dinv, const float* __restrict__ bias_in,
    const float* __restrict__ W, __half* __restrict__ Tout, int n)
{
    __shared__ float wlds[64 * F_OUT];
    int tid = threadIdx.x;
    for (int i = tid; i < 64 * F_OUT; i += 256) wlds[i] = W[i];  // k-major
    __syncthreads();

    int l = tid & 7;              // lane within octet
    int f0 = l * 8;               // this lane's 8 feats (in and out)
    int slot = tid >> 3;          // 32 octets/block
    int node = blockIdx.x * 32 + slot;
    bool valid = node < n;        // octet-uniform

    if (valid) {
        float acc[8];
        float di = dinv[node];
        float sc = di * di;
        uint4 ts = *(const uint4*)&Tin[node * 64 + f0];
        {
            const __half2* th = (const __half2*)&ts;
            #pragma unroll
            for (int m = 0; m < 4; ++m) {
                float2 tf = __half22float2(th[m]);
                acc[2 * m]     = tf.x * sc;       // self loop
                acc[2 * m + 1] = tf.y * sc;
            }
        }

        int s0 = rowstart[node], c = cnt[node];
        for (int j = 0; j < c; j += 8) {
            int idx = j + l;
            int2 cw = (idx < c) ? csr[s0 + idx] : make_int2(0, 0);
            int   col[8]; float w[8];
            #pragma unroll
            for (int u = 0; u < 8; ++u) {
                col[u] = __shfl(cw.x, u, 8);
                w[u]   = __int_as_float(__shfl(cw.y, u, 8));
            }
            uint4 tv[8];
            #pragma unroll
            for (int u = 0; u < 8; ++u)
                tv[u] = *(const uint4*)&Tin[col[u] * 64 + f0];
            #pragma unroll
            for (int u = 0; u < 8; ++u) {
                const __half2* hh = (const __half2*)&tv[u];
                #pragma unroll
                for (int m = 0; m < 4; ++m) {
                    float2 tf = __half22float2(hh[m]);
                    acc[2 * m]     += w[u] * tf.x;
                    acc[2 * m + 1] += w[u] * tf.y;
                }
            }
        }

        // bias + relu on the aggregated input row
        float4 ba = *(const float4*)&bias_in[f0];
        float4 bb = *(const float4*)&bias_in[f0 + 4];
        acc[0] = fmaxf(acc[0] + ba.x, 0.f);
        acc[1] = fmaxf(acc[1] + ba.y, 0.f);
        acc[2] = fmaxf(acc[2] + ba.z, 0.f);
        acc[3] = fmaxf(acc[3] + ba.w, 0.f);
        acc[4] = fmaxf(acc[4] + bb.x, 0.f);
        acc[5] = fmaxf(acc[5] + bb.y, 0.f);
        acc[6] = fmaxf(acc[6] + bb.z, 0.f);
        acc[7] = fmaxf(acc[7] + bb.w, 0.f);

        // octet GEMM: lane kb holds k=kb*8..kb*8+7 of the row; broadcast
        // via shuffles, each lane accumulates its 8 output feats.
        float o[8] = {};
        bool fcomp = (f0 < F_OUT);      // F_OUT=40: lanes 5..7 emit zeros
        #pragma unroll
        for (int kb = 0; kb < 8; ++kb) {
            float gk[8];
            #pragma unroll
            for (int m = 0; m < 8; ++m) gk[m] = __shfl(acc[m], kb, 8);
            if (fcomp) {
                #pragma unroll
                for (int m = 0; m < 8; ++m) {
                    int k = kb * 8 + m;
                    float4 wa = *(const float4*)&wlds[k * F_OUT + f0];
                    float4 wb = *(const float4*)&wlds[k * F_OUT + f0 + 4];
                    o[0] += gk[m] * wa.x;  o[1] += gk[m] * wa.y;
                    o[2] += gk[m] * wa.z;  o[3] += gk[m] * wa.w;
                    o[4] += gk[m] * wb.x;  o[5] += gk[m] * wb.y;
                    o[6] += gk[m] * wb.z;  o[7] += gk[m] * wb.w;
                }
            }
        }

        __half2 h[4];
        #pragma unroll
        for (int m = 0; m < 4; ++m) h[m] = __floats2half2_rn(o[2 * m], o[2 * m + 1]);
        *(uint4*)&Tout[node * 64 + f0] = *(uint4*)h;   // stride 64 always
    }
}

// ======== final gather (octet): fp16 tC (stride 64, 40 live) -> fp32 out ==

__global__ __launch_bounds__(256, 4) void k_gather_out(
    const __half* __restrict__ T, const int2* __restrict__ csr,
    const int* __restrict__ rowstart, const int* __restrict__ cnt,
    const float* __restrict__ dinv, const float* __restrict__ bias,
    float* __restrict__ OUT, int n)
{
    int tid = threadIdx.x;
    int l = tid & 7, f0 = l * 8;
    int slot = tid >> 3;
    int node = blockIdx.x * 32 + slot;
    if (node >= n) return;            // octet-uniform

    float acc[8];
    float di = dinv[node];
    float sc = di * di;
    uint4 ts = *(const uint4*)&T[node * 64 + f0];
    {
        const __half2* th = (const __half2*)&ts;
        #pragma unroll
        for (int m = 0; m < 4; ++m) {
            float2 tf = __half22float2(th[m]);
            acc[2 * m]     = tf.x * sc;
            acc[2 * m + 1] = tf.y * sc;
        }
    }

    int s0 = rowstart[node], c = cnt[node];
    for (int j = 0; j < c; j += 8) {
        int idx = j + l;
        int2 cw = (idx < c) ? csr[s0 + idx] : make_int2(0, 0);
        int   col[8]; float w[8];
        #pragma unroll
        for (int u = 0; u < 8; ++u) {
            col[u] = __shfl(cw.x, u, 8);
            w[u]   = __int_as_float(__shfl(cw.y, u, 8));
        }
        uint4 tv[8];
        #pragma unroll
        for (int u = 0; u < 8; ++u)
            tv[u] = *(const uint4*)&T[col[u] * 64 + f0];
        #pragma unroll
        for (int u = 0; u < 8; ++u) {
            const __half2* hh = (const __half2*)&tv[u];
            #pragma unroll
            for (int m = 0; m < 4; ++m) {
                float2 tf = __half22float2(hh[m]);
                acc[2 * m]     += w[u] * tf.x;
                acc[2 * m + 1] += w[u] * tf.y;
            }
        }
    }

    if (f0 < 40) {                    // lanes 0..4 hold live feats
        float4 oa, ob;
        float4 ba = *(const float4*)&bias[f0];
        float4 bb = *(const float4*)&bias[f0 + 4];
        oa.x = acc[0] + ba.x;  oa.y = acc[1] + ba.y;
        oa.z = acc[2] + ba.z;  oa.w = acc[3] + ba.w;
        ob.x = acc[4] + bb.x;  ob.y = acc[5] + bb.y;
        ob.z = acc[6] + bb.z;  ob.w = acc[7] + bb.w;
        *(float4*)&OUT[node * 40 + f0]     = oa;
        *(float4*)&OUT[node * 40 + f0 + 4] = ob;
    }
}

// ---------------- launch ----------------

extern "C" void kernel_launch(void* const* d_in, const int* in_sizes, int n_in,
                              void* d_out, int out_size, void* d_ws, size_t ws_size,
                              hipStream_t stream) {
    const float* x  = (const float*)d_in[0];
    const int*   ei = (const int*)d_in[1];
    const float* W1 = (const float*)d_in[2];
    const float* b1 = (const float*)d_in[3];
    const float* W2 = (const float*)d_in[4];
    const float* b2 = (const float*)d_in[5];
    const float* W3 = (const float*)d_in[6];
    const float* b3 = (const float*)d_in[7];
    float* out = (float*)d_out;

    const int N = NN, E = NE;
    const int* src = ei;
    const int* dst = ei + E;

    // workspace layout (24.8 MB):
    //   partial (9.8MB) is dead after k_scatter -> tB aliases its start.
    //   tA is dead after fused<64> -> tC aliases tA.
    int*    cnt      = (int*)d_ws;                           // N
    int*    rowstart = cnt + N;                               // N
    float*  dinv     = (float*)(rowstart + N);                // N
    int*    sums     = (int*)(dinv + N);                      // 256
    unsigned short* lrank = (unsigned short*)(sums + 256);    // E
    int2*   csr      = (int2*)(lrank + E);                    // E
    unsigned int* partial = (unsigned int*)(csr + E);         // NB*HW (9.8MB)
    __half* tA       = (__half*)(partial + (size_t)NB * HW);  // N*64 fp16
    __half* tB       = (__half*)partial;                      // N*64 (aliases)
    __half* tC       = tA;                                    // N*64 (aliases)

    int eb4 = (E / 4 + 255) / 256;  // 782
    int nb  = (N + 255) / 256;      // 196
    int gb  = (N + 63) / 64;        // 782 (64 nodes/block)
    int snb = (HW + 255) / 256;     // 98 scan blocks
    int fb  = (N + 31) / 32;        // 1563 (32 nodes/block, octet kernels)

    k_hist<<<NB, 256, 0, stream>>>(dst, partial, lrank, E);
    k_gemm1_scan<<<gb + snb, 256, 0, stream>>>(x, W1, tA, N, partial, cnt, gb);
    k_scan1 <<<nb, 256, 0, stream>>>(cnt, rowstart, sums, N);
    k_scan23<<<nb, 256, 0, stream>>>(sums, rowstart, cnt, dinv, N);
    k_scatter<<<eb4, 256, 0, stream>>>(src, dst, lrank, partial, rowstart, dinv, csr, E);

    k_fused<64><<<fb, 256, 0, stream>>>(tA, csr, rowstart, cnt, dinv, b1, W2, tB, N);
    k_fused<40><<<fb, 256, 0, stream>>>(tB, csr, rowstart, cnt, dinv, b2, W3, tC, N);
    k_gather_out<<<fb, 256, 0, stream>>>(tC, csr, rowstart, cnt, dinv, b3, out, N);
}

// Round 4
// 230.639 us; speedup vs baseline: 1.3832x; 1.0193x over previous
//
#include <hip/hip_runtime.h>
#include <hip/hip_fp16.h>

#define NN 50000
#define NE 800000
#define CHUNK 8192            // edges per hist block (2^13; scatter uses >>13)
#define NB 98                 // ceil(NE/CHUNK)
#define HW 25000              // packed histogram words = ceil(NN/2)

// ======== k_hist: per-chunk LDS histogram, ZERO global atomics ========
// 50K bins as 2x uint16 packed per uint32 -> 100KB LDS (1 block/CU).
// LDS atomicAdd returns old packed word => local rank of the edge within
// (chunk, dst). Per-chunk-per-node count <= 8192 so halves never carry.

__global__ __launch_bounds__(256) void k_hist(
    const int* __restrict__ dst, unsigned int* __restrict__ partial,
    unsigned short* __restrict__ lrank, int E)
{
    __shared__ unsigned int hb[HW];
    int tid = threadIdx.x, b = blockIdx.x;
    for (int i = tid; i < HW; i += 256) hb[i] = 0;
    __syncthreads();

    int base = b * CHUNK;
    int end  = min(base + CHUNK, E);
    for (int e = base + tid; e < end; e += 256) {
        int d = dst[e];
        unsigned sh  = (unsigned)(d & 1) << 4;
        unsigned old = atomicAdd(&hb[d >> 1], 1u << sh);
        lrank[e] = (unsigned short)((old >> sh) & 0xFFFFu);
    }
    __syncthreads();

    unsigned int* prow = partial + (size_t)b * HW;
    for (int i = tid; i < HW; i += 256) prow[i] = hb[i];
}

// ======== gemm1 (x@W1 -> fp16 T) merged with partial-matrix scan ====
// SCAN BLOCKS FIRST (blockIdx < scanBlocks): they carry a 98-long serial
// dependency, so they must start at t=0 and run UNDER the gemm, not after
// it. Loads batched 7-wide (98 = 14x7) for memory-level parallelism.
// GEMM BLOCKS: 64 nodes/block, 4-node x 4-feat reg tile, explicit
// two-stage register double buffer on the A loads (4 loads always in
// flight while FMAs run).

__global__ __launch_bounds__(256) void k_gemm1_scan(
    const float* __restrict__ A, const float* __restrict__ W,
    __half* __restrict__ T, int n,
    unsigned int* __restrict__ partial, int* __restrict__ cnt, int scanBlocks)
{
    __shared__ float wlds[128 * 64];     // 32KB (scan blocks ignore)
    int tid = threadIdx.x;

    if ((int)blockIdx.x < scanBlocks) {
        int w = (int)blockIdx.x * 256 + tid;
        if (w < HW) {
            unsigned s0 = 0, s1 = 0;
            unsigned int* p = partial + w;
            #pragma unroll 1
            for (int t = 0; t < 14; ++t) {             // 14 tiles x 7
                size_t base = (size_t)(t * 7) * HW;
                unsigned v[7];
                #pragma unroll
                for (int u = 0; u < 7; ++u) v[u] = p[base + (size_t)u * HW];
                #pragma unroll
                for (int u = 0; u < 7; ++u) {
                    unsigned nv = v[u];
                    p[base + (size_t)u * HW] = s0 | (s1 << 16);  // exclusive
                    s0 += nv & 0xFFFFu;
                    s1 += nv >> 16;
                }
            }
            int d1 = w * 2 + 1;
            cnt[w * 2] = (int)s0;
            if (d1 < n) cnt[d1] = (int)s1;
        }
        return;
    }

    const int K = 128;
    for (int i = tid; i < (K * 64) / 4; i += 256)      // float4 staging
        ((float4*)wlds)[i] = ((const float4*)W)[i];
    __syncthreads();

    int fg = tid & 15;            // feats fg*4 .. fg*4+3
    int slot = tid >> 4;          // 16 slots x 4 nodes = 64 nodes/block
    int nodebase = ((int)blockIdx.x - scanBlocks) * 64 + slot * 4;

    float4 acc[4] = {};
    float4 a0[4], a1[4];

    #pragma unroll
    for (int r = 0; r < 4; ++r) {
        int node = nodebase + r;
        a0[r] = (node < n) ? *(const float4*)&A[node * K + 0]
                           : float4{0.f, 0.f, 0.f, 0.f};
    }

    #pragma unroll 1
    for (int k = 0; k < K; k += 8) {
        #pragma unroll
        for (int r = 0; r < 4; ++r) {
            int node = nodebase + r;
            a1[r] = (node < n) ? *(const float4*)&A[node * K + k + 4]
                               : float4{0.f, 0.f, 0.f, 0.f};
        }
        #pragma unroll
        for (int kk = 0; kk < 4; ++kk) {
            float4 wv = *(const float4*)&wlds[(k + kk) * 64 + fg * 4];
            #pragma unroll
            for (int r = 0; r < 4; ++r) {
                float av = (kk == 0) ? a0[r].x : (kk == 1) ? a0[r].y
                         : (kk == 2) ? a0[r].z : a0[r].w;
                acc[r].x += av * wv.x;
                acc[r].y += av * wv.y;
                acc[r].z += av * wv.z;
                acc[r].w += av * wv.w;
            }
        }
        if (k + 8 < K) {
            #pragma unroll
            for (int r = 0; r < 4; ++r) {
                int node = nodebase + r;
                a0[r] = (node < n) ? *(const float4*)&A[node * K + k + 8]
                                   : float4{0.f, 0.f, 0.f, 0.f};
            }
        }
        #pragma unroll
        for (int kk = 0; kk < 4; ++kk) {
            float4 wv = *(const float4*)&wlds[(k + 4 + kk) * 64 + fg * 4];
            #pragma unroll
            for (int r = 0; r < 4; ++r) {
                float av = (kk == 0) ? a1[r].x : (kk == 1) ? a1[r].y
                         : (kk == 2) ? a1[r].z : a1[r].w;
                acc[r].x += av * wv.x;
                acc[r].y += av * wv.y;
                acc[r].z += av * wv.z;
                acc[r].w += av * wv.w;
            }
        }
    }

    #pragma unroll
    for (int r = 0; r < 4; ++r) {
        int node = nodebase + r;
        if (node < n) {
            __half2 h[2];
            h[0] = __floats2half2_rn(acc[r].x, acc[r].y);
            h[1] = __floats2half2_rn(acc[r].z, acc[r].w);
            *(uint2*)&T[node * 64 + fg * 4] = *(uint2*)h;
        }
    }
}

// ======== scans (unchanged) ========

__global__ __launch_bounds__(256) void k_scan1(const int* __restrict__ cnt,
                                               int* __restrict__ rowstart,
                                               int* __restrict__ sums, int n) {
    __shared__ int s[256];
    int t = threadIdx.x, gid = blockIdx.x * 256 + t;
    int v = (gid < n) ? cnt[gid] : 0;
    s[t] = v; __syncthreads();
    for (int off = 1; off < 256; off <<= 1) {
        int x = (t >= off) ? s[t - off] : 0;
        __syncthreads();
        s[t] += x; __syncthreads();
    }
    if (gid < n) rowstart[gid] = s[t] - v;
    if (t == 255) sums[blockIdx.x] = s[t];
}

__global__ __launch_bounds__(256) void k_scan23(const int* __restrict__ sums,
                                                int* __restrict__ rowstart,
                                                const int* __restrict__ cnt,
                                                float* __restrict__ dinv, int n) {
    __shared__ int s[256];
    int t = threadIdx.x, b = blockIdx.x;
    s[t] = (t < b) ? sums[t] : 0;
    __syncthreads();
    for (int off = 128; off > 0; off >>= 1) {
        if (t < off) s[t] += s[t + off];
        __syncthreads();
    }
    int prefix = s[0];
    int gid = b * 256 + t;
    if (gid < n) {
        rowstart[gid] += prefix;
        dinv[gid] = rsqrtf((float)cnt[gid] + 1.0f);
    }
}

// ======== scatter: atomic-free (unchanged) ========

__global__ __launch_bounds__(256) void k_scatter(const int* __restrict__ src,
                                                 const int* __restrict__ dst,
                                                 const unsigned short* __restrict__ lrank,
                                                 const unsigned int* __restrict__ partial,
                                                 const int* __restrict__ rowstart,
                                                 const float* __restrict__ dinv,
                                                 int2* __restrict__ csr, int E) {
    int base = ((int)blockIdx.x * 256 + threadIdx.x) * 4;
    if (base < E) {
        const unsigned int* prow = partial + (size_t)(base >> 13) * HW;
        int4 s4 = *(const int4*)&src[base];
        int4 d4 = *(const int4*)&dst[base];
        uint2 l2 = *(const uint2*)&lrank[base];
        int s[4] = {s4.x, s4.y, s4.z, s4.w};
        int d[4] = {d4.x, d4.y, d4.z, d4.w};
        unsigned lr[4] = {l2.x & 0xFFFFu, l2.x >> 16, l2.y & 0xFFFFu, l2.y >> 16};
        #pragma unroll
        for (int u = 0; u < 4; ++u) {
            unsigned off = (prow[d[u] >> 1] >> ((unsigned)(d[u] & 1) << 4)) & 0xFFFFu;
            int p = rowstart[d[u]] + (int)off + (int)lr[u];
            float w = dinv[s[u]] * dinv[d[u]];
            csr[p] = make_int2(s[u], __float_as_int(w));
        }
    }
}

// ======== fused octet kernel (unchanged from R3) ========

template <int F_OUT>
__global__ __launch_bounds__(256, 4) void k_fused(
    const __half* __restrict__ Tin, const int2* __restrict__ csr,
    const int* __restrict__ rowstart, const int* __restrict__ cnt,
    const float* __restrict__ dinv, const float* __restrict__ bias_in,
    const float* __restrict__ W, __half* __restrict__ Tout, int n)
{
    __shared__ float wlds[64 * F_OUT];
    int tid = threadIdx.x;
    for (int i = tid; i < 64 * F_OUT; i += 256) wlds[i] = W[i];  // k-major
    __syncthreads();

    int l = tid & 7;              // lane within octet
    int f0 = l * 8;               // this lane's 8 feats (in and out)
    int slot = tid >> 3;          // 32 octets/block
    int node = blockIdx.x * 32 + slot;
    bool valid = node < n;        // octet-uniform

    if (valid) {
        float acc[8];
        float di = dinv[node];
        float sc = di * di;
        uint4 ts = *(const uint4*)&Tin[node * 64 + f0];
        {
            const __half2* th = (const __half2*)&ts;
            #pragma unroll
            for (int m = 0; m < 4; ++m) {
                float2 tf = __half22float2(th[m]);
                acc[2 * m]     = tf.x * sc;       // self loop
                acc[2 * m + 1] = tf.y * sc;
            }
        }

        int s0 = rowstart[node], c = cnt[node];
        for (int j = 0; j < c; j += 8) {
            int idx = j + l;
            int2 cw = (idx < c) ? csr[s0 + idx] : make_int2(0, 0);
            int   col[8]; float w[8];
            #pragma unroll
            for (int u = 0; u < 8; ++u) {
                col[u] = __shfl(cw.x, u, 8);
                w[u]   = __int_as_float(__shfl(cw.y, u, 8));
            }
            uint4 tv[8];
            #pragma unroll
            for (int u = 0; u < 8; ++u)
                tv[u] = *(const uint4*)&Tin[col[u] * 64 + f0];
            #pragma unroll
            for (int u = 0; u < 8; ++u) {
                const __half2* hh = (const __half2*)&tv[u];
                #pragma unroll
                for (int m = 0; m < 4; ++m) {
                    float2 tf = __half22float2(hh[m]);
                    acc[2 * m]     += w[u] * tf.x;
                    acc[2 * m + 1] += w[u] * tf.y;
                }
            }
        }

        // bias + relu on the aggregated input row
        float4 ba = *(const float4*)&bias_in[f0];
        float4 bb = *(const float4*)&bias_in[f0 + 4];
        acc[0] = fmaxf(acc[0] + ba.x, 0.f);
        acc[1] = fmaxf(acc[1] + ba.y, 0.f);
        acc[2] = fmaxf(acc[2] + ba.z, 0.f);
        acc[3] = fmaxf(acc[3] + ba.w, 0.f);
        acc[4] = fmaxf(acc[4] + bb.x, 0.f);
        acc[5] = fmaxf(acc[5] + bb.y, 0.f);
        acc[6] = fmaxf(acc[6] + bb.z, 0.f);
        acc[7] = fmaxf(acc[7] + bb.w, 0.f);

        // octet GEMM: lane kb holds k=kb*8..kb*8+7 of the row; broadcast
        // via shuffles, each lane accumulates its 8 output feats.
        float o[8] = {};
        bool fcomp = (f0 < F_OUT);      // F_OUT=40: lanes 5..7 emit zeros
        #pragma unroll
        for (int kb = 0; kb < 8; ++kb) {
            float gk[8];
            #pragma unroll
            for (int m = 0; m < 8; ++m) gk[m] = __shfl(acc[m], kb, 8);
            if (fcomp) {
                #pragma unroll
                for (int m = 0; m < 8; ++m) {
                    int k = kb * 8 + m;
                    float4 wa = *(const float4*)&wlds[k * F_OUT + f0];
                    float4 wb = *(const float4*)&wlds[k * F_OUT + f0 + 4];
                    o[0] += gk[m] * wa.x;  o[1] += gk[m] * wa.y;
                    o[2] += gk[m] * wa.z;  o[3] += gk[m] * wa.w;
                    o[4] += gk[m] * wb.x;  o[5] += gk[m] * wb.y;
                    o[6] += gk[m] * wb.z;  o[7] += gk[m] * wb.w;
                }
            }
        }

        __half2 h[4];
        #pragma unroll
        for (int m = 0; m < 4; ++m) h[m] = __floats2half2_rn(o[2 * m], o[2 * m + 1]);
        *(uint4*)&Tout[node * 64 + f0] = *(uint4*)h;   // stride 64 always
    }
}

// ======== final gather (octet, unchanged from R3) ========

__global__ __launch_bounds__(256, 4) void k_gather_out(
    const __half* __restrict__ T, const int2* __restrict__ csr,
    const int* __restrict__ rowstart, const int* __restrict__ cnt,
    const float* __restrict__ dinv, const float* __restrict__ bias,
    float* __restrict__ OUT, int n)
{
    int tid = threadIdx.x;
    int l = tid & 7, f0 = l * 8;
    int slot = tid >> 3;
    int node = blockIdx.x * 32 + slot;
    if (node >= n) return;            // octet-uniform

    float acc[8];
    float di = dinv[node];
    float sc = di * di;
    uint4 ts = *(const uint4*)&T[node * 64 + f0];
    {
        const __half2* th = (const __half2*)&ts;
        #pragma unroll
        for (int m = 0; m < 4; ++m) {
            float2 tf = __half22float2(th[m]);
            acc[2 * m]     = tf.x * sc;
            acc[2 * m + 1] = tf.y * sc;
        }
    }

    int s0 = rowstart[node], c = cnt[node];
    for (int j = 0; j < c; j += 8) {
        int idx = j + l;
        int2 cw = (idx < c) ? csr[s0 + idx] : make_int2(0, 0);
        int   col[8]; float w[8];
        #pragma unroll
        for (int u = 0; u < 8; ++u) {
            col[u] = __shfl(cw.x, u, 8);
            w[u]   = __int_as_float(__shfl(cw.y, u, 8));
        }
        uint4 tv[8];
        #pragma unroll
        for (int u = 0; u < 8; ++u)
            tv[u] = *(const uint4*)&T[col[u] * 64 + f0];
        #pragma unroll
        for (int u = 0; u < 8; ++u) {
            const __half2* hh = (const __half2*)&tv[u];
            #pragma unroll
            for (int m = 0; m < 4; ++m) {
                float2 tf = __half22float2(hh[m]);
                acc[2 * m]     += w[u] * tf.x;
                acc[2 * m + 1] += w[u] * tf.y;
            }
        }
    }

    if (f0 < 40) {                    // lanes 0..4 hold live feats
        float4 oa, ob;
        float4 ba = *(const float4*)&bias[f0];
        float4 bb = *(const float4*)&bias[f0 + 4];
        oa.x = acc[0] + ba.x;  oa.y = acc[1] + ba.y;
        oa.z = acc[2] + ba.z;  oa.w = acc[3] + ba.w;
        ob.x = acc[4] + bb.x;  ob.y = acc[5] + bb.y;
        ob.z = acc[6] + bb.z;  ob.w = acc[7] + bb.w;
        *(float4*)&OUT[node * 40 + f0]     = oa;
        *(float4*)&OUT[node * 40 + f0 + 4] = ob;
    }
}

// ---------------- launch ----------------

extern "C" void kernel_launch(void* const* d_in, const int* in_sizes, int n_in,
                              void* d_out, int out_size, void* d_ws, size_t ws_size,
                              hipStream_t stream) {
    const float* x  = (const float*)d_in[0];
    const int*   ei = (const int*)d_in[1];
    const float* W1 = (const float*)d_in[2];
    const float* b1 = (const float*)d_in[3];
    const float* W2 = (const float*)d_in[4];
    const float* b2 = (const float*)d_in[5];
    const float* W3 = (const float*)d_in[6];
    const float* b3 = (const float*)d_in[7];
    float* out = (float*)d_out;

    const int N = NN, E = NE;
    const int* src = ei;
    const int* dst = ei + E;

    // workspace layout (24.8 MB):
    //   partial (9.8MB) is dead after k_scatter -> tB aliases its start.
    //   tA is dead after fused<64> -> tC aliases tA.
    int*    cnt      = (int*)d_ws;                           // N
    int*    rowstart = cnt + N;                               // N
    float*  dinv     = (float*)(rowstart + N);                // N
    int*    sums     = (int*)(dinv + N);                      // 256
    unsigned short* lrank = (unsigned short*)(sums + 256);    // E
    int2*   csr      = (int2*)(lrank + E);                    // E
    unsigned int* partial = (unsigned int*)(csr + E);         // NB*HW (9.8MB)
    __half* tA       = (__half*)(partial + (size_t)NB * HW);  // N*64 fp16
    __half* tB       = (__half*)partial;                      // N*64 (aliases)
    __half* tC       = tA;                                    // N*64 (aliases)

    int eb4 = (E / 4 + 255) / 256;  // 782
    int nb  = (N + 255) / 256;      // 196
    int gb  = (N + 63) / 64;        // 782 (64 nodes/block)
    int snb = (HW + 255) / 256;     // 98 scan blocks (FIRST in grid)
    int fb  = (N + 31) / 32;        // 1563 (32 nodes/block, octet kernels)

    k_hist<<<NB, 256, 0, stream>>>(dst, partial, lrank, E);
    k_gemm1_scan<<<snb + gb, 256, 0, stream>>>(x, W1, tA, N, partial, cnt, snb);
    k_scan1 <<<nb, 256, 0, stream>>>(cnt, rowstart, sums, N);
    k_scan23<<<nb, 256, 0, stream>>>(sums, rowstart, cnt, dinv, N);
    k_scatter<<<eb4, 256, 0, stream>>>(src, dst, lrank, partial, rowstart, dinv, csr, E);

    k_fused<64><<<fb, 256, 0, stream>>>(tA, csr, rowstart, cnt, dinv, b1, W2, tB, N);
    k_fused<40><<<fb, 256, 0, stream>>>(tB, csr, rowstart, cnt, dinv, b2, W3, tC, N);
    k_gather_out<<<fb, 256, 0, stream>>>(tC, csr, rowstart, cnt, dinv, b3, out, N);
}